// Round 1
// 823.894 us; speedup vs baseline: 1.3762x; 1.3762x over previous
//
#include <hip/hip_runtime.h>
#include <hip/hip_bf16.h>

typedef __hip_bfloat16 bf16;

#define N_NODES  100000
#define EMBED    64
#define N_EDGES  3200000
#define ND       6400000
#define N_LAYERS 3
#define NBLK     391        // ceil(N_NODES/256)

// bucketed CSR build
#define PNB  256            // number of dst buckets
#define BSZ  391            // nodes per bucket (256*391 = 100096 >= N_NODES)
#define EPB  4096           // edges per partition block

// flags: [0] edge_nz  [1] emb_outl

__global__ void k_flags0(int* f) {
    int i = threadIdx.x;
    if (i < 16) f[i] = 0;
}

// int64 [2,E] viewed as i32 words: odd words (high halves) all zero.
__global__ void k_scan_edge(const int* __restrict__ edge, int* __restrict__ fl) {
    long long step = (long long)gridDim.x * blockDim.x;
    int found = 0;
    for (long long j = (long long)blockIdx.x * blockDim.x + threadIdx.x;
         j < N_EDGES; j += step)
        if (edge[2 * j + 1] != 0) found = 1;
    if (found) atomicOr(&fl[0], 1);
}

// bf16 census (safety; expected fp32)
__global__ void k_scan_emb(const unsigned short* __restrict__ u, int* __restrict__ fl) {
    long long step = (long long)gridDim.x * blockDim.x;
    int local = 0;
    for (long long j = (long long)blockIdx.x * blockDim.x + threadIdx.x;
         j < ND; j += step) {
        unsigned b = (u[j] >> 8) & 0x7f;
        if (b < 0x2e || b > 0x41) local++;
    }
    if (local) atomicAdd(&fl[1], local);
}

__device__ __forceinline__ int is_i64(const int* fl) { return fl[0] == 0; }
__device__ __forceinline__ int rd_src(const int* e, int i64, int k) {
    return i64 ? e[2 * k] : e[k];
}
__device__ __forceinline__ int rd_dst(const int* e, int i64, int k) {
    return i64 ? e[2 * (N_EDGES + k)] : e[N_EDGES + k];
}
__device__ __forceinline__ int clampid(int v) {
    return (v < 0) ? 0 : ((v >= N_NODES) ? (N_NODES - 1) : v);
}
__device__ __forceinline__ float rd_emb(const void* emb, const int* fl, int i) {
    if (fl[1] < (ND / 16)) return __bfloat162float(((const bf16*)emb)[i]);
    return ((const float*)emb)[i];
}

__global__ void k_zero_i(int* __restrict__ p, int n) {
    int i = blockIdx.x * blockDim.x + threadIdx.x;
    if (i < n) p[i] = 0;
}

// ---- coarse bucket counts (LDS hist, 256 bins) ----
__global__ void __launch_bounds__(256) k_bcnt(const int* __restrict__ edge,
                                              const int* __restrict__ fl,
                                              int* __restrict__ bcnt) {
    __shared__ int h[PNB];
    int t = threadIdx.x;
    h[t] = 0;
    __syncthreads();
    int i64 = is_i64(fl);
    int step = gridDim.x * 256;
    for (int e = blockIdx.x * 256 + t; e < N_EDGES; e += step) {
        int d = clampid(rd_dst(edge, i64, e));
        atomicAdd(&h[d / BSZ], 1);
    }
    __syncthreads();
    if (h[t]) atomicAdd(&bcnt[t], h[t]);
}

__global__ void k_bscan(const int* __restrict__ bcnt, int* __restrict__ bbase,
                        int* __restrict__ bcur) {
    if (threadIdx.x == 0 && blockIdx.x == 0) {
        int r = 0;
        for (int i = 0; i < PNB; i++) { bbase[i] = r; bcur[i] = r; r += bcnt[i]; }
        bbase[PNB] = r;
    }
}

// ---- partition edges into dst-buckets, LDS counting sort per 4096-edge block ----
__global__ void __launch_bounds__(256) k_part(const int* __restrict__ edge,
                                              const int* __restrict__ fl,
                                              int* __restrict__ bcur,
                                              uint2* __restrict__ pairs) {
    __shared__ int h[PNB];
    __shared__ int excl[PNB];
    __shared__ int gbase[PNB];
    __shared__ int lcur[PNB];
    __shared__ uint2 st[EPB];
    __shared__ unsigned char binof[EPB];
    int t = threadIdx.x;
    int e0 = blockIdx.x * EPB;
    int nval = N_EDGES - e0;
    if (nval > EPB) nval = EPB;
    int i64 = is_i64(fl);

    h[t] = 0;
    __syncthreads();
    // count
    for (int k = t; k < nval; k += 256) {
        int d = clampid(rd_dst(edge, i64, e0 + k));
        atomicAdd(&h[d / BSZ], 1);
    }
    __syncthreads();
    // Hillis-Steele inclusive scan over 256 bins
    int c = h[t];
    excl[t] = c;
    __syncthreads();
    for (int off = 1; off < 256; off <<= 1) {
        int v = (t >= off) ? excl[t - off] : 0;
        __syncthreads();
        excl[t] += v;
        __syncthreads();
    }
    int myexcl = excl[t] - c;
    __syncthreads();
    excl[t] = myexcl;                                   // exclusive scan
    gbase[t] = (c > 0) ? atomicAdd(&bcur[t], c) : 0;    // reserve global span
    lcur[t] = myexcl;
    __syncthreads();
    // scatter into LDS, ordered by bucket
    for (int k = t; k < nval; k += 256) {
        int s = clampid(rd_src(edge, i64, e0 + k));
        int d = clampid(rd_dst(edge, i64, e0 + k));
        int b = d / BSZ;
        int lp = atomicAdd(&lcur[b], 1);
        st[lp] = make_uint2((unsigned)s, (unsigned)d);
        binof[lp] = (unsigned char)b;
    }
    __syncthreads();
    // flush: runs of same-bucket pairs -> contiguous global spans (coalesced)
    for (int k = t; k < nval; k += 256) {
        int b = binof[k];
        pairs[gbase[b] + (k - excl[b])] = st[k];
    }
}

// ---- per-node degree from bucketed pairs (LDS hist, plain coalesced stores) ----
__global__ void __launch_bounds__(1024) k_bhist(const uint2* __restrict__ pairs,
                                                const int* __restrict__ bbase,
                                                int* __restrict__ cnt) {
    __shared__ int hh[BSZ];
    int b = blockIdx.x;
    int t = threadIdx.x;
    for (int i = t; i < BSZ; i += 1024) hh[i] = 0;
    __syncthreads();
    int beg = bbase[b], end = bbase[b + 1];
    int base = b * BSZ;
    for (int i = beg + t; i < end; i += 1024)
        atomicAdd(&hh[(int)pairs[i].y - base], 1);
    __syncthreads();
    for (int i = t; i < BSZ; i += 1024) {
        int n = base + i;
        if (n < N_NODES) cnt[n] = hh[i];
    }
}

__global__ void k_dis(const int* __restrict__ cnt, float* __restrict__ dis) {
    int i = blockIdx.x * blockDim.x + threadIdx.x;
    if (i < N_NODES) {
        int d = cnt[i];
        dis[i] = (d > 0) ? rsqrtf((float)d) : 0.0f;
    }
}

// two-level exclusive scan of cnt -> rowptr
__global__ void k_scanA(const int* __restrict__ cnt, int* __restrict__ bsum) {
    __shared__ int red[256];
    int t = threadIdx.x;
    int i = blockIdx.x * 256 + t;
    red[t] = (i < N_NODES) ? cnt[i] : 0;
    __syncthreads();
    for (int s = 128; s > 0; s >>= 1) {
        if (t < s) red[t] += red[t + s];
        __syncthreads();
    }
    if (t == 0) bsum[blockIdx.x] = red[0];
}

__global__ void k_scanB(const int* __restrict__ bsum, int* __restrict__ boff) {
    if (threadIdx.x == 0 && blockIdx.x == 0) {
        int r = 0;
        for (int i = 0; i < NBLK; i++) { boff[i] = r; r += bsum[i]; }
    }
}

__global__ void k_scanC(const int* __restrict__ cnt, const int* __restrict__ boff,
                        int* __restrict__ rowptr) {
    __shared__ int tmp[256];
    int t = threadIdx.x;
    int i = blockIdx.x * 256 + t;
    int c = (i < N_NODES) ? cnt[i] : 0;
    tmp[t] = c;
    __syncthreads();
    for (int off = 1; off < 256; off <<= 1) {
        int v = (t >= off) ? tmp[t - off] : 0;
        __syncthreads();
        tmp[t] += v;
        __syncthreads();
    }
    int excl = tmp[t] - c + boff[blockIdx.x];
    if (i < N_NODES) rowptr[i] = excl;
    if (i == N_NODES - 1) rowptr[N_NODES] = N_EDGES;  // clamp => every edge lands
}

// ---- final placement: one block per bucket, cursors in LDS, writes stay in a
// ~50KB csr window owned by one CU (no global atomics, ~1 writeback per line) ----
__global__ void __launch_bounds__(1024) k_bplace(const uint2* __restrict__ pairs,
                                                 const int* __restrict__ bbase,
                                                 const int* __restrict__ rowptr,
                                                 int* __restrict__ csr) {
    __shared__ int lcur[BSZ];
    int b = blockIdx.x;
    int t = threadIdx.x;
    int base = b * BSZ;
    for (int i = t; i < BSZ; i += 1024) {
        int n = base + i;
        lcur[i] = (n < N_NODES) ? rowptr[n] : 0;
    }
    __syncthreads();
    int beg = bbase[b], end = bbase[b + 1];
    for (int i = beg + t; i < end; i += 1024) {
        uint2 p = pairs[i];
        int pos = atomicAdd(&lcur[(int)p.y - base], 1);
        csr[pos] = (int)p.x;
    }
}

// out (fp32, = d_out) = emb; Y0 = bf16(dis ⊙ emb)
__global__ void k_init(const void* __restrict__ emb, const int* __restrict__ fl,
                       const float* __restrict__ dis,
                       float* __restrict__ out, bf16* __restrict__ Y) {
    int i = blockIdx.x * blockDim.x + threadIdx.x;
    if (i < ND) {
        float v = rd_emb(emb, fl, i);
        out[i] = v;
        Y[i] = __float2bfloat16(dis[i >> 6] * v);
    }
}

// wave-per-row SpMM, fused epilogue. mode: 0 = mid layer (out+=x, Yout), 1 = last.
__global__ void __launch_bounds__(256) k_spmm(
        const int* __restrict__ rowptr, const int* __restrict__ csr,
        const float* __restrict__ dis, const bf16* __restrict__ Yin,
        float* __restrict__ out, bf16* __restrict__ Yout, int last) {
    int wave = threadIdx.x >> 6;
    int lane = threadIdx.x & 63;
    int n = blockIdx.x * 4 + wave;
    if (n >= N_NODES) return;
    int beg = rowptr[n];
    int end = rowptr[n + 1];
    float acc = 0.0f;
    int j = beg;
    for (; j + 1 < end; j += 2) {
        int s0 = csr[j];
        int s1 = csr[j + 1];
        float a = __bfloat162float(Yin[s0 * EMBED + lane]);
        float b = __bfloat162float(Yin[s1 * EMBED + lane]);
        acc += a + b;
    }
    if (j < end) acc += __bfloat162float(Yin[csr[j] * EMBED + lane]);
    float dn = dis[n];
    float x = dn * acc;
    int i = n * EMBED + lane;
    if (last) {
        out[i] = (out[i] + x) * 0.25f;
    } else {
        out[i] = out[i] + x;
        Yout[i] = __float2bfloat16(dn * x);
    }
}

__global__ void k_fill42(float* __restrict__ o) {
    int i = blockIdx.x * blockDim.x + threadIdx.x;
    if (i < ND) o[i] = 42.0f;   // signature: ws too small for CSR layout
}

extern "C" void kernel_launch(void* const* d_in, const int* in_sizes, int n_in,
                              void* d_out, int out_size, void* d_ws, size_t ws_size,
                              hipStream_t stream) {
    const void* emb = d_in[0];
    const int* edge = (const int*)d_in[1];
    float* out = (float*)d_out;

    const int B = 256;
    const int gN  = (N_NODES + B - 1) / B;      // 391
    const int gND = (ND + B - 1) / B;           // 25000
    const int gP  = (N_EDGES + EPB - 1) / EPB;  // 782 partition blocks
    const int gW  = (N_NODES + 3) / 4;          // 25000 (wave-per-row)

    char* ws = (char*)d_ws;
    int* fl = (int*)ws;
    size_t off = 256;
    const size_t off_cnt    = off;                 off += (size_t)N_NODES * 4;
    const size_t off_dis    = off;                 off += (size_t)N_NODES * 4;
    const size_t off_rowptr = off;                 off += (size_t)(N_NODES + 1) * 4;
    const size_t off_cursor = off;                 off += (size_t)N_NODES * 4;   // bkt arrays live here
    const size_t off_bsum   = off;                 off += (size_t)NBLK * 4;
    const size_t off_boff   = off;                 off += (size_t)NBLK * 4 + 252; // keeps off_Y0 8B-aligned
    const size_t off_csr    = off;                 off += (size_t)N_EDGES * 4;
    const size_t off_Y0     = off;                 off += (size_t)ND * 2;
    const size_t off_Y1     = off;                 off += (size_t)ND * 2;
    const size_t need = off;                       // ~40.0 MB

    if (ws_size < need) {
        k_fill42<<<gND, B, 0, stream>>>(out);
        return;
    }

    int*   cnt    = (int*)(ws + off_cnt);
    float* dis    = (float*)(ws + off_dis);
    int*   rowptr = (int*)(ws + off_rowptr);
    int*   bcnt   = (int*)(ws + off_cursor);           // 256 ints
    int*   bbase  = (int*)(ws + off_cursor + 1024);    // 257 ints
    int*   bcur   = (int*)(ws + off_cursor + 4096);    // 256 ints
    int*   bsum   = (int*)(ws + off_bsum);
    int*   boff   = (int*)(ws + off_boff);
    int*   csr    = (int*)(ws + off_csr);
    uint2* pairs  = (uint2*)(ws + off_Y0);             // 25.6MB, reuses Y0+Y1 (dead until k_init)
    bf16*  Y0     = (bf16*)(ws + off_Y0);
    bf16*  Y1     = (bf16*)(ws + off_Y1);

    k_flags0<<<1, 64, 0, stream>>>(fl);
    k_scan_edge<<<1024, B, 0, stream>>>(edge, fl);
    k_scan_emb<<<1024, B, 0, stream>>>((const unsigned short*)emb, fl);

    // bucketed CSR build
    k_zero_i<<<1, B, 0, stream>>>(bcnt, PNB);
    k_bcnt<<<1024, B, 0, stream>>>(edge, fl, bcnt);
    k_bscan<<<1, 64, 0, stream>>>(bcnt, bbase, bcur);
    k_part<<<gP, B, 0, stream>>>(edge, fl, bcur, pairs);
    k_bhist<<<PNB, 1024, 0, stream>>>(pairs, bbase, cnt);
    k_dis<<<gN, B, 0, stream>>>(cnt, dis);
    k_scanA<<<NBLK, B, 0, stream>>>(cnt, bsum);
    k_scanB<<<1, 64, 0, stream>>>(bsum, boff);
    k_scanC<<<NBLK, B, 0, stream>>>(cnt, boff, rowptr);
    k_bplace<<<PNB, 1024, 0, stream>>>(pairs, bbase, rowptr, csr);

    k_init<<<gND, B, 0, stream>>>(emb, fl, dis, out, Y0);

    k_spmm<<<gW, B, 0, stream>>>(rowptr, csr, dis, Y0, out, Y1, 0);
    k_spmm<<<gW, B, 0, stream>>>(rowptr, csr, dis, Y1, out, Y0, 0);
    k_spmm<<<gW, B, 0, stream>>>(rowptr, csr, dis, Y0, out, Y1, 1);
}

// Round 3
// 594.987 us; speedup vs baseline: 1.9057x; 1.3847x over previous
//
#include <hip/hip_runtime.h>
#include <hip/hip_bf16.h>

typedef __hip_bfloat16 bf16;

#define N_NODES  100000
#define EMBED    64
#define N_EDGES  3200000
#define ND       6400000
#define N_LAYERS 3
#define NBLK     391        // ceil(N_NODES/256)

// bucketed CSR build
#define PNB  256            // number of dst buckets
#define BSZ  391            // nodes per bucket (256*391 = 100096 >= N_NODES)
#define EPB  4096           // edges per partition block

// flags: [0] edge_nz  [1] emb_outl

__global__ void k_flags0(int* f) {
    int i = threadIdx.x;
    if (i < 16) f[i] = 0;
}

// int64 [2,E] viewed as i32 words: odd words (high halves) all zero.
__global__ void k_scan_edge(const int* __restrict__ edge, int* __restrict__ fl) {
    long long step = (long long)gridDim.x * blockDim.x;
    int found = 0;
    for (long long j = (long long)blockIdx.x * blockDim.x + threadIdx.x;
         j < N_EDGES; j += step)
        if (edge[2 * j + 1] != 0) found = 1;
    if (found) atomicOr(&fl[0], 1);
}

// bf16 census (safety; expected fp32)
__global__ void k_scan_emb(const unsigned short* __restrict__ u, int* __restrict__ fl) {
    long long step = (long long)gridDim.x * blockDim.x;
    int local = 0;
    for (long long j = (long long)blockIdx.x * blockDim.x + threadIdx.x;
         j < ND; j += step) {
        unsigned b = (u[j] >> 8) & 0x7f;
        if (b < 0x2e || b > 0x41) local++;
    }
    if (local) atomicAdd(&fl[1], local);
}

__device__ __forceinline__ int is_i64(const int* fl) { return fl[0] == 0; }
__device__ __forceinline__ int rd_src(const int* e, int i64, int k) {
    return i64 ? e[2 * k] : e[k];
}
__device__ __forceinline__ int rd_dst(const int* e, int i64, int k) {
    return i64 ? e[2 * (N_EDGES + k)] : e[N_EDGES + k];
}
__device__ __forceinline__ int clampid(int v) {
    return (v < 0) ? 0 : ((v >= N_NODES) ? (N_NODES - 1) : v);
}
__device__ __forceinline__ float rd_emb(const void* emb, const int* fl, int i) {
    if (fl[1] < (ND / 16)) return __bfloat162float(((const bf16*)emb)[i]);
    return ((const float*)emb)[i];
}

__global__ void k_zero_i(int* __restrict__ p, int n) {
    int i = blockIdx.x * blockDim.x + threadIdx.x;
    if (i < n) p[i] = 0;
}

// ---- coarse bucket counts (LDS hist, 256 bins) ----
__global__ void __launch_bounds__(256) k_bcnt(const int* __restrict__ edge,
                                              const int* __restrict__ fl,
                                              int* __restrict__ bcnt) {
    __shared__ int h[PNB];
    int t = threadIdx.x;
    h[t] = 0;
    __syncthreads();
    int i64 = is_i64(fl);
    int step = gridDim.x * 256;
    for (int e = blockIdx.x * 256 + t; e < N_EDGES; e += step) {
        int d = clampid(rd_dst(edge, i64, e));
        atomicAdd(&h[d / BSZ], 1);
    }
    __syncthreads();
    if (h[t]) atomicAdd(&bcnt[t], h[t]);
}

__global__ void k_bscan(const int* __restrict__ bcnt, int* __restrict__ bbase,
                        int* __restrict__ bcur) {
    if (threadIdx.x == 0 && blockIdx.x == 0) {
        int r = 0;
        for (int i = 0; i < PNB; i++) { bbase[i] = r; bcur[i] = r; r += bcnt[i]; }
        bbase[PNB] = r;
    }
}

// ---- partition edges into dst-buckets, LDS counting sort per 4096-edge block ----
__global__ void __launch_bounds__(256) k_part(const int* __restrict__ edge,
                                              const int* __restrict__ fl,
                                              int* __restrict__ bcur,
                                              uint2* __restrict__ pairs) {
    __shared__ int h[PNB];
    __shared__ int excl[PNB];
    __shared__ int gbase[PNB];
    __shared__ int lcur[PNB];
    __shared__ uint2 st[EPB];
    __shared__ unsigned char binof[EPB];
    int t = threadIdx.x;
    int e0 = blockIdx.x * EPB;
    int nval = N_EDGES - e0;
    if (nval > EPB) nval = EPB;
    int i64 = is_i64(fl);

    h[t] = 0;
    __syncthreads();
    // count
    for (int k = t; k < nval; k += 256) {
        int d = clampid(rd_dst(edge, i64, e0 + k));
        atomicAdd(&h[d / BSZ], 1);
    }
    __syncthreads();
    // Hillis-Steele inclusive scan over 256 bins
    int c = h[t];
    excl[t] = c;
    __syncthreads();
    for (int off = 1; off < 256; off <<= 1) {
        int v = (t >= off) ? excl[t - off] : 0;
        __syncthreads();
        excl[t] += v;
        __syncthreads();
    }
    int myexcl = excl[t] - c;
    __syncthreads();
    excl[t] = myexcl;                                   // exclusive scan
    gbase[t] = (c > 0) ? atomicAdd(&bcur[t], c) : 0;    // reserve global span
    lcur[t] = myexcl;
    __syncthreads();
    // scatter into LDS, ordered by bucket
    for (int k = t; k < nval; k += 256) {
        int s = clampid(rd_src(edge, i64, e0 + k));
        int d = clampid(rd_dst(edge, i64, e0 + k));
        int b = d / BSZ;
        int lp = atomicAdd(&lcur[b], 1);
        st[lp] = make_uint2((unsigned)s, (unsigned)d);
        binof[lp] = (unsigned char)b;
    }
    __syncthreads();
    // flush: runs of same-bucket pairs -> contiguous global spans (coalesced)
    for (int k = t; k < nval; k += 256) {
        int b = binof[k];
        pairs[gbase[b] + (k - excl[b])] = st[k];
    }
}

// ---- per-node degree from bucketed pairs (LDS hist, plain coalesced stores) ----
__global__ void __launch_bounds__(1024) k_bhist(const uint2* __restrict__ pairs,
                                                const int* __restrict__ bbase,
                                                int* __restrict__ cnt) {
    __shared__ int hh[BSZ];
    int b = blockIdx.x;
    int t = threadIdx.x;
    for (int i = t; i < BSZ; i += 1024) hh[i] = 0;
    __syncthreads();
    int beg = bbase[b], end = bbase[b + 1];
    int base = b * BSZ;
    for (int i = beg + t; i < end; i += 1024)
        atomicAdd(&hh[(int)pairs[i].y - base], 1);
    __syncthreads();
    for (int i = t; i < BSZ; i += 1024) {
        int n = base + i;
        if (n < N_NODES) cnt[n] = hh[i];
    }
}

__global__ void k_dis(const int* __restrict__ cnt, float* __restrict__ dis) {
    int i = blockIdx.x * blockDim.x + threadIdx.x;
    if (i < N_NODES) {
        int d = cnt[i];
        dis[i] = (d > 0) ? rsqrtf((float)d) : 0.0f;
    }
}

// two-level exclusive scan of cnt -> rowptr
__global__ void k_scanA(const int* __restrict__ cnt, int* __restrict__ bsum) {
    __shared__ int red[256];
    int t = threadIdx.x;
    int i = blockIdx.x * 256 + t;
    red[t] = (i < N_NODES) ? cnt[i] : 0;
    __syncthreads();
    for (int s = 128; s > 0; s >>= 1) {
        if (t < s) red[t] += red[t + s];
        __syncthreads();
    }
    if (t == 0) bsum[blockIdx.x] = red[0];
}

__global__ void k_scanB(const int* __restrict__ bsum, int* __restrict__ boff) {
    if (threadIdx.x == 0 && blockIdx.x == 0) {
        int r = 0;
        for (int i = 0; i < NBLK; i++) { boff[i] = r; r += bsum[i]; }
    }
}

__global__ void k_scanC(const int* __restrict__ cnt, const int* __restrict__ boff,
                        int* __restrict__ rowptr) {
    __shared__ int tmp[256];
    int t = threadIdx.x;
    int i = blockIdx.x * 256 + t;
    int c = (i < N_NODES) ? cnt[i] : 0;
    tmp[t] = c;
    __syncthreads();
    for (int off = 1; off < 256; off <<= 1) {
        int v = (t >= off) ? tmp[t - off] : 0;
        __syncthreads();
        tmp[t] += v;
        __syncthreads();
    }
    int excl = tmp[t] - c + boff[blockIdx.x];
    if (i < N_NODES) rowptr[i] = excl;
    if (i == N_NODES - 1) rowptr[N_NODES] = N_EDGES;  // clamp => every edge lands
}

// ---- final placement: one block per bucket, cursors in LDS ----
__global__ void __launch_bounds__(1024) k_bplace(const uint2* __restrict__ pairs,
                                                 const int* __restrict__ bbase,
                                                 const int* __restrict__ rowptr,
                                                 int* __restrict__ csr) {
    __shared__ int lcur[BSZ];
    int b = blockIdx.x;
    int t = threadIdx.x;
    int base = b * BSZ;
    for (int i = t; i < BSZ; i += 1024) {
        int n = base + i;
        lcur[i] = (n < N_NODES) ? rowptr[n] : 0;
    }
    __syncthreads();
    int beg = bbase[b], end = bbase[b + 1];
    for (int i = beg + t; i < end; i += 1024) {
        uint2 p = pairs[i];
        int pos = atomicAdd(&lcur[(int)p.y - base], 1);
        csr[pos] = (int)p.x;
    }
}

// out (fp32, = d_out) = emb; Y0 = bf16(dis ⊙ emb)
__global__ void k_init(const void* __restrict__ emb, const int* __restrict__ fl,
                       const float* __restrict__ dis,
                       float* __restrict__ out, bf16* __restrict__ Y) {
    int i = blockIdx.x * blockDim.x + threadIdx.x;
    if (i < ND) {
        float v = rd_emb(emb, fl, i);
        out[i] = v;
        Y[i] = __float2bfloat16(dis[i >> 6] * v);
    }
}

// wave-per-row SpMM, 16 lanes per edge (uint2 = 4 bf16 per lane), 8 edges per
// inner step => ~16 random 128B transactions in flight per wave (vs 2 before).
// mode: last=0 mid layer (out+=x, Yout), last=1 final (*0.25).
__global__ void __launch_bounds__(256) k_spmm(
        const int* __restrict__ rowptr, const int* __restrict__ csr,
        const float* __restrict__ dis, const bf16* __restrict__ Yin,
        float* __restrict__ out, bf16* __restrict__ Yout, int last) {
    int wave = threadIdx.x >> 6;
    int lane = threadIdx.x & 63;
    int q    = lane >> 4;        // quarter: which edge of a group of 4
    int l16  = lane & 15;        // col group: cols 4*l16 .. 4*l16+3
    int n = blockIdx.x * 4 + wave;
    if (n >= N_NODES) return;
    int beg = rowptr[n];
    int end = rowptr[n + 1];
    const unsigned* Yu = (const unsigned*)Yin;   // 2 bf16 per word
    float a0 = 0.f, a1 = 0.f, a2 = 0.f, a3 = 0.f;
    int j = beg;
    for (; j + 8 <= end; j += 8) {
        int s0 = csr[j + q];
        int s1 = csr[j + 4 + q];
        uint2 v0 = *(const uint2*)(Yu + s0 * 32 + l16 * 2);
        uint2 v1 = *(const uint2*)(Yu + s1 * 32 + l16 * 2);
        a0 += __uint_as_float(v0.x << 16);
        a1 += __uint_as_float(v0.x & 0xffff0000u);
        a2 += __uint_as_float(v0.y << 16);
        a3 += __uint_as_float(v0.y & 0xffff0000u);
        a0 += __uint_as_float(v1.x << 16);
        a1 += __uint_as_float(v1.x & 0xffff0000u);
        a2 += __uint_as_float(v1.y << 16);
        a3 += __uint_as_float(v1.y & 0xffff0000u);
    }
    if (j + q < end) {
        int s = csr[j + q];
        uint2 v = *(const uint2*)(Yu + s * 32 + l16 * 2);
        a0 += __uint_as_float(v.x << 16);
        a1 += __uint_as_float(v.x & 0xffff0000u);
        a2 += __uint_as_float(v.y << 16);
        a3 += __uint_as_float(v.y & 0xffff0000u);
    }
    if (j + 4 + q < end) {
        int s = csr[j + 4 + q];
        uint2 v = *(const uint2*)(Yu + s * 32 + l16 * 2);
        a0 += __uint_as_float(v.x << 16);
        a1 += __uint_as_float(v.x & 0xffff0000u);
        a2 += __uint_as_float(v.y << 16);
        a3 += __uint_as_float(v.y & 0xffff0000u);
    }
    // combine the 4 quarters: lanes l, l^16, l^32, l^48 hold the same cols
    a0 += __shfl_xor(a0, 16); a0 += __shfl_xor(a0, 32);
    a1 += __shfl_xor(a1, 16); a1 += __shfl_xor(a1, 32);
    a2 += __shfl_xor(a2, 16); a2 += __shfl_xor(a2, 32);
    a3 += __shfl_xor(a3, 16); a3 += __shfl_xor(a3, 32);
    if (lane < 16) {
        float dn = dis[n];
        float x0 = dn * a0, x1 = dn * a1, x2 = dn * a2, x3 = dn * a3;
        int i4 = n * 16 + l16;                 // float4 index into out
        float4 o = ((const float4*)out)[i4];
        if (last) {
            o.x = (o.x + x0) * 0.25f;
            o.y = (o.y + x1) * 0.25f;
            o.z = (o.z + x2) * 0.25f;
            o.w = (o.w + x3) * 0.25f;
            ((float4*)out)[i4] = o;
        } else {
            o.x += x0; o.y += x1; o.z += x2; o.w += x3;
            ((float4*)out)[i4] = o;
            bf16 t0 = __float2bfloat16(dn * x0);
            bf16 t1 = __float2bfloat16(dn * x1);
            bf16 t2 = __float2bfloat16(dn * x2);
            bf16 t3 = __float2bfloat16(dn * x3);
            ushort4 yv;
            yv.x = *(unsigned short*)&t0;
            yv.y = *(unsigned short*)&t1;
            yv.z = *(unsigned short*)&t2;
            yv.w = *(unsigned short*)&t3;
            *(ushort4*)(Yout + n * EMBED + 4 * l16) = yv;
        }
    }
}

__global__ void k_fill42(float* __restrict__ o) {
    int i = blockIdx.x * blockDim.x + threadIdx.x;
    if (i < ND) o[i] = 42.0f;   // signature: ws too small for CSR layout
}

extern "C" void kernel_launch(void* const* d_in, const int* in_sizes, int n_in,
                              void* d_out, int out_size, void* d_ws, size_t ws_size,
                              hipStream_t stream) {
    const void* emb = d_in[0];
    const int* edge = (const int*)d_in[1];
    float* out = (float*)d_out;

    const int B = 256;
    const int gN  = (N_NODES + B - 1) / B;      // 391
    const int gND = (ND + B - 1) / B;           // 25000
    const int gP  = (N_EDGES + EPB - 1) / EPB;  // 782 partition blocks
    const int gW  = (N_NODES + 3) / 4;          // 25000 (wave-per-row)

    char* ws = (char*)d_ws;
    int* fl = (int*)ws;
    size_t off = 256;
    const size_t off_cnt    = off;                 off += (size_t)N_NODES * 4;
    const size_t off_dis    = off;                 off += (size_t)N_NODES * 4;
    const size_t off_rowptr = off;                 off += (size_t)(N_NODES + 1) * 4;
    const size_t off_cursor = off;                 off += (size_t)N_NODES * 4;   // bkt arrays live here
    const size_t off_bsum   = off;                 off += (size_t)NBLK * 4;
    const size_t off_boff   = off;                 off += (size_t)NBLK * 4 + 252; // keeps off_Y0 8B-aligned
    const size_t off_csr    = off;                 off += (size_t)N_EDGES * 4;
    const size_t off_Y0     = off;                 off += (size_t)ND * 2;
    const size_t off_Y1     = off;                 off += (size_t)ND * 2;
    const size_t need = off;                       // ~40.0 MB

    if (ws_size < need) {
        k_fill42<<<gND, B, 0, stream>>>(out);
        return;
    }

    int*   cnt    = (int*)(ws + off_cnt);
    float* dis    = (float*)(ws + off_dis);
    int*   rowptr = (int*)(ws + off_rowptr);
    int*   bcnt   = (int*)(ws + off_cursor);           // 256 ints
    int*   bbase  = (int*)(ws + off_cursor + 1024);    // 257 ints
    int*   bcur   = (int*)(ws + off_cursor + 4096);    // 256 ints
    int*   bsum   = (int*)(ws + off_bsum);
    int*   boff   = (int*)(ws + off_boff);
    int*   csr    = (int*)(ws + off_csr);
    uint2* pairs  = (uint2*)(ws + off_Y0);             // 25.6MB, reuses Y0+Y1 (dead until k_init)
    bf16*  Y0     = (bf16*)(ws + off_Y0);
    bf16*  Y1     = (bf16*)(ws + off_Y1);

    k_flags0<<<1, 64, 0, stream>>>(fl);
    k_scan_edge<<<1024, B, 0, stream>>>(edge, fl);
    k_scan_emb<<<1024, B, 0, stream>>>((const unsigned short*)emb, fl);

    // bucketed CSR build
    k_zero_i<<<1, B, 0, stream>>>(bcnt, PNB);
    k_bcnt<<<1024, B, 0, stream>>>(edge, fl, bcnt);
    k_bscan<<<1, 64, 0, stream>>>(bcnt, bbase, bcur);
    k_part<<<gP, B, 0, stream>>>(edge, fl, bcur, pairs);
    k_bhist<<<PNB, 1024, 0, stream>>>(pairs, bbase, cnt);
    k_dis<<<gN, B, 0, stream>>>(cnt, dis);
    k_scanA<<<NBLK, B, 0, stream>>>(cnt, bsum);
    k_scanB<<<1, 64, 0, stream>>>(bsum, boff);
    k_scanC<<<NBLK, B, 0, stream>>>(cnt, boff, rowptr);
    k_bplace<<<PNB, 1024, 0, stream>>>(pairs, bbase, rowptr, csr);

    k_init<<<gND, B, 0, stream>>>(emb, fl, dis, out, Y0);

    k_spmm<<<gW, B, 0, stream>>>(rowptr, csr, dis, Y0, out, Y1, 0);
    k_spmm<<<gW, B, 0, stream>>>(rowptr, csr, dis, Y1, out, Y0, 0);
    k_spmm<<<gW, B, 0, stream>>>(rowptr, csr, dis, Y0, out, Y1, 1);
}